// Round 2
// baseline (241.425 us; speedup 1.0000x reference)
//
#include <hip/hip_runtime.h>

#define LEAKY(x) ((x) > 0.0f ? (x) : 0.01f * (x))

typedef __attribute__((ext_vector_type(8))) short bf16x8;      // MFMA A/B frag
typedef __attribute__((ext_vector_type(4))) float f32x4;       // MFMA C/D frag
typedef __attribute__((ext_vector_type(8))) unsigned short u16x8;
typedef __attribute__((ext_vector_type(4))) unsigned short u16x4;

__device__ __forceinline__ unsigned short f2bf(float f) {
    unsigned int u = __float_as_uint(f);
    unsigned int r = (u + 0x7fffu + ((u >> 16) & 1u)) >> 16;   // RNE
    return (unsigned short)r;
}
__device__ __forceinline__ float bf2f(unsigned short u) {
    return __uint_as_float(((unsigned int)u) << 16);
}

// async global->LDS DMA, 16B per lane. LDS dest is WAVE-UNIFORM base + lane*16;
// global src is per-lane (carries the inverse swizzle).
#define GLD16(gp, lp) __builtin_amdgcn_global_load_lds( \
    (__attribute__((address_space(1))) void*)(gp), \
    (__attribute__((address_space(3))) void*)(lp), 16, 0, 0)

// ---------------- small builds ----------------

// wide max via atomicMax (values > 0 so uint ordering == float ordering); grid 64
__global__ void k_dmax(const float* __restrict__ deadline, float* __restrict__ dmax) {
    int t = threadIdx.x;
    float m = deadline[blockIdx.x * 256 + t];
    for (int off = 32; off > 0; off >>= 1) m = fmaxf(m, __shfl_down(m, off));
    __shared__ float s[4];
    if ((t & 63) == 0) s[t >> 6] = m;
    __syncthreads();
    if (t == 0) atomicMax((unsigned int*)dmax,
                          __float_as_uint(fmaxf(fmaxf(s[0], s[1]), fmaxf(s[2], s[3]))));
}

// rowsum + 64-slot atomicMax partials of r=1/dist; R is NOT materialized
__global__ __launch_bounds__(256) void k_rowstats(const float* __restrict__ loc,
                                                  const float* __restrict__ deadline,
                                                  const float* __restrict__ dmaxv,
                                                  float* __restrict__ rowsum, float* __restrict__ pmax64) {
    int blk = blockIdx.x;                       // 0..4095
    int wave = threadIdx.x >> 6, lane = threadIdx.x & 63;
    int bi = blk * 4 + wave;                    // b*512 + i
    int b = bi >> 9, i = bi & 511;
    float invd = 1.0f / (*dmaxv);
    const float* lb = loc + b * 1024;
    const float* db = deadline + b * 512;
    float xi = lb[i * 2], yi = lb[i * 2 + 1], zi = db[i] * invd;
    float lsum = 0.f, lmax = 0.f;
    for (int j = lane; j < 512; j += 64) {
        float d0 = xi - lb[j * 2], d1 = yi - lb[j * 2 + 1], d2 = zi - db[j] * invd;
        float dd = d0 * d0 + d1 * d1 + d2 * d2;
        float r = (j == i) ? 0.f : rsqrtf(dd);
        lsum += r; lmax = fmaxf(lmax, r);
    }
    for (int off = 32; off > 0; off >>= 1) {
        lsum += __shfl_down(lsum, off);
        lmax = fmaxf(lmax, __shfl_down(lmax, off));
    }
    __shared__ float smax[4];
    if (lane == 0) { rowsum[bi] = lsum; smax[wave] = lmax; }
    __syncthreads();
    if (threadIdx.x == 0) {
        float m = fmaxf(fmaxf(smax[0], smax[1]), fmaxf(smax[2], smax[3]));
        atomicMax((unsigned int*)(pmax64 + (blk & 63)), __float_as_uint(m));
    }
}

// fused build: [0,8192) L ; [8192,14336) F0 powers ; [14336,16064) WgT repack
__global__ __launch_bounds__(256) void k_build(
    const float* __restrict__ loc, const float* __restrict__ deadline,
    const float* __restrict__ dmaxv, const float* __restrict__ rowsum,
    const float* __restrict__ pmax64,
    const float* __restrict__ Wi, const float* __restrict__ bi_,
    const float* __restrict__ Wg1, const float* __restrict__ Wg2, const float* __restrict__ Wg3,
    unsigned short* __restrict__ Lb,
    unsigned short* __restrict__ P1, unsigned short* __restrict__ P2, unsigned short* __restrict__ P3,
    unsigned short* __restrict__ WgT)
{
    __shared__ float amaxS;
    int blk = blockIdx.x;
    int t = threadIdx.x;
    if (blk < 8192) {
        // ---- L bf16 (symmetric), recompute r on the fly: 4 j's per thread ----
        if (t < 64) {
            float m = pmax64[t];
            for (int off = 32; off > 0; off >>= 1) m = fmaxf(m, __shfl_down(m, off));
            if (t == 0) amaxS = m;
        }
        __syncthreads();
        float inv = 1.0f / amaxS;
        float invd = 1.0f / (*dmaxv);
        int id = blk * 256 + t;
        size_t e = (size_t)id * 4;
        size_t bi = e >> 9;
        int b = (int)(bi >> 9);
        int i = (int)(bi & 511);
        int j0 = (int)(e & 511);
        const float* lb = loc + b * 1024;
        const float* db = deadline + b * 512;
        float xi = lb[i * 2], yi = lb[i * 2 + 1], zi = db[i] * invd;
        float4 l01 = *(const float4*)(lb + j0 * 2);
        float4 l23 = *(const float4*)(lb + j0 * 2 + 4);
        float4 dj = *(const float4*)(db + j0);
        float diag = rowsum[bi] * inv - 1.0f;
        float jx[4] = {l01.x, l01.z, l23.x, l23.z};
        float jy[4] = {l01.y, l01.w, l23.y, l23.w};
        float jz[4] = {dj.x * invd, dj.y * invd, dj.z * invd, dj.w * invd};
        u16x4 o;
#pragma unroll
        for (int j = 0; j < 4; j++) {
            float d0 = xi - jx[j], d1 = yi - jy[j], d2 = zi - jz[j];
            float dd = d0 * d0 + d1 * d1 + d2 * d2;
            float v = (i == j0 + j) ? diag : -rsqrtf(dd) * inv;
            o[j] = f2bf(v);
        }
        *(u16x4*)(Lb + e) = o;
    } else if (blk < 14336) {
        // ---- F0 powers, bf16 row-major [16384][384] x3, 4 cols per thread ----
        int id = (blk - 8192) * 256 + t;          // 1,572,864
        int row = id / 96, c4 = (id % 96) * 4;
        float x0 = loc[row * 2], x1 = loc[row * 2 + 1], x2 = deadline[row] / (*dmaxv);
        float4 w0 = *(const float4*)(Wi + c4);
        float4 w1 = *(const float4*)(Wi + 384 + c4);
        float4 w2 = *(const float4*)(Wi + 768 + c4);
        float4 bb = *(const float4*)(bi_ + c4);
        float f[4] = {x0 * w0.x + x1 * w1.x + x2 * w2.x + bb.x,
                      x0 * w0.y + x1 * w1.y + x2 * w2.y + bb.y,
                      x0 * w0.z + x1 * w1.z + x2 * w2.z + bb.z,
                      x0 * w0.w + x1 * w1.w + x2 * w2.w + bb.w};
        u16x4 o1, o2, o3;
#pragma unroll
        for (int j = 0; j < 4; j++) {
            o1[j] = f2bf(f[j]); o2[j] = f2bf(f[j] * f[j]); o3[j] = f2bf(f[j] * f[j] * f[j]);
        }
        size_t e = (size_t)row * 384 + c4;
        *(u16x4*)(P1 + e) = o1; *(u16x4*)(P2 + e) = o2; *(u16x4*)(P3 + e) = o3;
    } else {
        // ---- WgT[part][g][k] = Wg{g/128}[(part*384+k)*128 + (g&127)] ----
        int id = (blk - 14336) * 256 + t;         // 442368 exact
        int part = id / 147456, rem = id % 147456;
        int g = rem / 384, k = rem % 384;
        int kp = g >> 7, n = g & 127;
        const float* W = (kp == 0) ? Wg1 : (kp == 1 ? Wg2 : Wg3);
        WgT[id] = f2bf(W[(part * 384 + k) * 128 + n]);
    }
}

// ---------------- pipelined MFMA cores (global_load_lds DMA staging) ----------------
// ONE barrier per K-iter; next tile's DMA issued right after the barrier so it flies
// under the MFMAs. Swizzle: LDS dest linear, global SOURCE pre-swizzled per lane with
// the same involution (chunk ^= row&7) the ds_read side uses.
// 128x128 tile: 4 waves 2x2, wave tile 64x64 (4x4 frags), 32 MFMA/wave/iter.

__device__ __forceinline__ void pipe128x128(
    const unsigned short* __restrict__ A0, int As0, const unsigned short* __restrict__ B0, int Bs0, int it0,
    const unsigned short* __restrict__ A1, int As1, const unsigned short* __restrict__ B1, int Bs1, int it1,
    unsigned short* AsL, unsigned short* BsL,   // each 16384 u16 (2 bufs x 8192)
    f32x4 (&acc)[4][4], int t)
{
    const int lane = t & 63, wave = t >> 6;
    const int wm = wave >> 1, wn = wave & 1;
    const int quad = lane >> 4, l16 = lane & 15;
    const int lrow = lane >> 3;                  // 0..7 row within 8-row stripe
    const int lsw  = ((lane & 7) ^ lrow) * 8;    // inverse-swizzled src chunk (u16 units)
    const int total = it0 + it1;

    auto stage = [&](int buf, const unsigned short* A, int As,
                     const unsigned short* B, int Bs, int k0) {
#pragma unroll
        for (int j = 0; j < 4; j++) {            // 128 rows A + 128 rows B, 8 rows/DMA
            int r0 = wave * 32 + j * 8;
            GLD16(A + (size_t)(r0 + lrow) * As + k0 + lsw, AsL + buf * 8192 + r0 * 64);
            GLD16(B + (size_t)(r0 + lrow) * Bs + k0 + lsw, BsL + buf * 8192 + r0 * 64);
        }
    };

    stage(0, A0, As0, B0, Bs0, 0);
    int buf = 0;
    for (int s = 0; s < total; s++) {
        __syncthreads();                          // vmcnt(0) drain -> buf ready
        if (s + 1 < total) {                      // next tile flies under the MFMAs
            int s2 = s + 1;
            int sg = (s2 >= it0);
            int k0 = (sg ? (s2 - it0) : s2) * 64;
            stage(buf ^ 1, sg ? A1 : A0, sg ? As1 : As0,
                            sg ? B1 : B0, sg ? Bs1 : Bs0, k0);
        }
#pragma unroll
        for (int h = 0; h < 2; h++) {
            bf16x8 af[4], bfr[4];
            int phys = ((h * 4 + quad) ^ (l16 & 7)) * 8;
#pragma unroll
            for (int i = 0; i < 4; i++)
                af[i] = *(const bf16x8*)(AsL + buf * 8192 + (wm * 64 + i * 16 + l16) * 64 + phys);
#pragma unroll
            for (int n = 0; n < 4; n++)
                bfr[n] = *(const bf16x8*)(BsL + buf * 8192 + (wn * 64 + n * 16 + l16) * 64 + phys);
#pragma unroll
            for (int i = 0; i < 4; i++)
#pragma unroll
                for (int n = 0; n < 4; n++)
                    acc[i][n] = __builtin_amdgcn_mfma_f32_16x16x32_bf16(af[i], bfr[n], acc[i][n], 0, 0, 0);
        }
        buf ^= 1;
    }
}

// 64x64 tile: wave tile 32x32 (2x2 frags), 8 MFMA/wave/iter
__device__ __forceinline__ void pipe64x64(
    const unsigned short* __restrict__ A0, int As0, const unsigned short* __restrict__ B0, int Bs0, int it0,
    unsigned short* AsL, unsigned short* BsL,   // 8192 / 8192 u16
    f32x4 (&acc)[2][2], int t)
{
    const int lane = t & 63, wave = t >> 6;
    const int wm = wave >> 1, wn = wave & 1;
    const int quad = lane >> 4, l16 = lane & 15;
    const int lrow = lane >> 3;
    const int lsw  = ((lane & 7) ^ lrow) * 8;

    auto stage = [&](int buf, int k0) {
#pragma unroll
        for (int j = 0; j < 2; j++) {
            int r0 = wave * 16 + j * 8;
            GLD16(A0 + (size_t)(r0 + lrow) * As0 + k0 + lsw, AsL + buf * 4096 + r0 * 64);
            GLD16(B0 + (size_t)(r0 + lrow) * Bs0 + k0 + lsw, BsL + buf * 4096 + r0 * 64);
        }
    };

    stage(0, 0);
    int buf = 0;
    for (int s = 0; s < it0; s++) {
        __syncthreads();
        if (s + 1 < it0) stage(buf ^ 1, (s + 1) * 64);
#pragma unroll
        for (int h = 0; h < 2; h++) {
            bf16x8 af[2], bfr[2];
            int phys = ((h * 4 + quad) ^ (l16 & 7)) * 8;
#pragma unroll
            for (int i = 0; i < 2; i++)
                af[i] = *(const bf16x8*)(AsL + buf * 4096 + (wm * 32 + i * 16 + l16) * 64 + phys);
#pragma unroll
            for (int n = 0; n < 2; n++)
                bfr[n] = *(const bf16x8*)(BsL + buf * 4096 + (wn * 32 + n * 16 + l16) * 64 + phys);
#pragma unroll
            for (int i = 0; i < 2; i++)
#pragma unroll
                for (int n = 0; n < 2; n++)
                    acc[i][n] = __builtin_amdgcn_mfma_f32_16x16x32_bf16(af[i], bfr[n], acc[i][n], 0, 0, 0);
        }
        buf ^= 1;
    }
}

// Y2^T[g][node] = WgT(p2)·P^T ; grid 384, id = b + 32*(kp*4+nb)
__global__ __launch_bounds__(256) void k_ygemmT(
    const unsigned short* __restrict__ WgT,
    const unsigned short* __restrict__ P1, const unsigned short* __restrict__ P2,
    const unsigned short* __restrict__ P3, unsigned short* __restrict__ Y2T)
{
    __shared__ unsigned short AsL[16384], BsL[16384];
    const int t = threadIdx.x;
    const int id = blockIdx.x;
    const int b = id & 31, tt = id >> 5;
    const int kp = tt >> 2, nb = tt & 3;
    const unsigned short* P = (kp == 0) ? P1 : (kp == 1 ? P2 : P3);
    f32x4 acc[4][4];
#pragma unroll
    for (int i = 0; i < 4; i++)
#pragma unroll
        for (int n = 0; n < 4; n++) acc[i][n] = (f32x4){0.f, 0.f, 0.f, 0.f};
    pipe128x128(WgT + ((size_t)2 * 384 + kp * 128) * 384, 384,
                P + ((size_t)b * 512 + nb * 128) * 384, 384, 6,
                nullptr, 0, nullptr, 0, 0, AsL, BsL, acc, t);

    const int wave = t >> 6, lane = t & 63;
    const int wm = wave >> 1, wn = wave & 1;
    const int quad = lane >> 4, l16 = lane & 15;
#pragma unroll
    for (int i = 0; i < 4; i++)
#pragma unroll
        for (int n = 0; n < 4; n++) {
            int g = kp * 128 + wm * 64 + i * 16 + quad * 4;
            int node = nb * 128 + wn * 64 + n * 16 + l16;
#pragma unroll
            for (int r = 0; r < 4; r++)
                Y2T[((size_t)b * 384 + g + r) * 512 + node] = f2bf(acc[i][n][r]);
        }
}

// Z^T = Y2T·L + WgT(p1)·P^T ; grid 384
__global__ __launch_bounds__(256) void k_lg1T(
    const unsigned short* __restrict__ Lb, const unsigned short* __restrict__ Y2T,
    const unsigned short* __restrict__ WgT,
    const unsigned short* __restrict__ P1, const unsigned short* __restrict__ P2,
    const unsigned short* __restrict__ P3, unsigned short* __restrict__ ZT)
{
    __shared__ unsigned short AsL[16384], BsL[16384];
    const int t = threadIdx.x;
    const int id = blockIdx.x;
    const int b = id & 31, tt = id >> 5;
    const int kp = tt >> 2, nb = tt & 3;
    const unsigned short* P = (kp == 0) ? P1 : (kp == 1 ? P2 : P3);
    f32x4 acc[4][4];
#pragma unroll
    for (int i = 0; i < 4; i++)
#pragma unroll
        for (int n = 0; n < 4; n++) acc[i][n] = (f32x4){0.f, 0.f, 0.f, 0.f};
    pipe128x128(Y2T + (size_t)b * 196608 + (size_t)kp * 128 * 512, 512,
                Lb + (size_t)b * 262144 + (size_t)nb * 128 * 512, 512, 8,
                WgT + ((size_t)1 * 384 + kp * 128) * 384, 384,
                P + ((size_t)b * 512 + nb * 128) * 384, 384, 6, AsL, BsL, acc, t);

    const int wave = t >> 6, lane = t & 63;
    const int wm = wave >> 1, wn = wave & 1;
    const int quad = lane >> 4, l16 = lane & 15;
#pragma unroll
    for (int i = 0; i < 4; i++)
#pragma unroll
        for (int n = 0; n < 4; n++) {
            int g = kp * 128 + wm * 64 + i * 16 + quad * 4;
            int node = nb * 128 + wn * 64 + n * 16 + l16;
#pragma unroll
            for (int r = 0; r < 4; r++)
                ZT[((size_t)b * 384 + g + r) * 512 + node] = f2bf(acc[i][n][r]);
        }
}

// F1 = leaky(L·Z + P·WgT(p0)^T + bias) + F0 ; fused BN sums ; grid 384, tt = gt*4+mb
__global__ __launch_bounds__(256) void k_lg2(
    const unsigned short* __restrict__ Lb, const unsigned short* __restrict__ ZT,
    const unsigned short* __restrict__ WgT,
    const unsigned short* __restrict__ P1, const unsigned short* __restrict__ P2,
    const unsigned short* __restrict__ P3,
    const float* __restrict__ bg1, const float* __restrict__ bg2, const float* __restrict__ bg3,
    unsigned short* __restrict__ F1b, float* __restrict__ bn1, float* __restrict__ bn2)
{
    __shared__ unsigned short AsL[16384], BsL[16384];
    __shared__ float bnS[128], bnQ[128];
    const int t = threadIdx.x;
    const int id = blockIdx.x;
    const int b = id & 31, tt = id >> 5;
    const int mb = tt & 3, gt = tt >> 2;          // mb: node tile(128), gt=kp: gcol tile(128) 0..2
    if (t < 128) { bnS[t] = 0.f; bnQ[t] = 0.f; }  // pipe's first barrier covers this
    const unsigned short* P = (gt == 0) ? P1 : (gt == 1 ? P2 : P3);
    f32x4 acc[4][4];
#pragma unroll
    for (int i = 0; i < 4; i++)
#pragma unroll
        for (int n = 0; n < 4; n++) acc[i][n] = (f32x4){0.f, 0.f, 0.f, 0.f};
    pipe128x128(Lb + (size_t)b * 262144 + (size_t)mb * 128 * 512, 512,
                ZT + (size_t)b * 196608 + (size_t)gt * 128 * 512, 512, 8,
                P + ((size_t)b * 512 + mb * 128) * 384, 384,
                WgT + (size_t)(gt * 128) * 384, 384, 6,
                AsL, BsL, acc, t);

    const int wave = t >> 6, lane = t & 63;
    const int wm = wave >> 1, wn = wave & 1;
    const int quad = lane >> 4, l16 = lane & 15;
    const float* bg = (gt == 0) ? bg1 : (gt == 1 ? bg2 : bg3);
    float ls1[4], ls2[4];
#pragma unroll
    for (int n = 0; n < 4; n++) { ls1[n] = 0.f; ls2[n] = 0.f; }
#pragma unroll
    for (int i = 0; i < 4; i++) {
        int rowl = mb * 128 + wm * 64 + i * 16 + quad * 4;
        size_t rowg = (size_t)b * 512 + rowl;
#pragma unroll
        for (int n = 0; n < 4; n++) {
            int nloc = wn * 64 + n * 16 + l16;    // 0..127
            int g = gt * 128 + nloc;
            float bias = bg[nloc];
#pragma unroll
            for (int r = 0; r < 4; r++) {
                size_t idx = (rowg + r) * 384 + g;
                float c = acc[i][n][r] + bias;
                float v = LEAKY(c) + bf2f(P1[idx]);   // residual +F0
                F1b[idx] = f2bf(v);
                ls1[n] += v; ls2[n] += v * v;
            }
        }
    }
#pragma unroll
    for (int n = 0; n < 4; n++) {
        int nloc = wn * 64 + n * 16 + l16;
        atomicAdd(&bnS[nloc], ls1[n]);
        atomicAdd(&bnQ[nloc], ls2[n]);
    }
    __syncthreads();
    if (t < 128) {
        atomicAdd(&bn1[gt * 128 + t], bnS[t]);
        atomicAdd(&bn2[gt * 128 + t], bnQ[t]);
    }
}

// merged: BN finish + fold scale into W_F^T (blocks 0..191) + effective bias (block 192)
__global__ __launch_bounds__(256) void k_bnfold(
    const float* __restrict__ bn1, const float* __restrict__ bn2,
    const float* __restrict__ gamma, const float* __restrict__ beta,
    const float* __restrict__ WF, const float* __restrict__ bF,
    unsigned short* __restrict__ WFsT, float* __restrict__ beffv)
{
    int blk = blockIdx.x;
    if (blk < 192) {                              // WFsT[n][k] = W_F[k][n]*sc[k]
        int id = blk * 256 + threadIdx.x;         // 49152
        int n = id / 384, k = id % 384;
        float mu = bn1[k] * (1.f / 16384.f);
        float var = bn2[k] * (1.f / 16384.f) - mu * mu;
        float sc = gamma[k] / sqrtf(var + 1e-5f);
        WFsT[id] = f2bf(WF[k * 128 + n] * sc);
    } else {                                      // beff[c] = bF[c] + sum_k ttL[k]*WF[k][c]
        __shared__ float ttL[384];
        int c = threadIdx.x;
        for (int k = c; k < 384; k += 256) {
            float mu = bn1[k] * (1.f / 16384.f);
            float var = bn2[k] * (1.f / 16384.f) - mu * mu;
            float sc = gamma[k] / sqrtf(var + 1e-5f);
            ttL[k] = beta[k] - mu * sc;
        }
        __syncthreads();
        if (c < 128) {
            float a = bF[c];
            for (int k = 0; k < 384; k++) a += ttL[k] * WF[k * 128 + c];
            beffv[c] = a;
        }
    }
}

// out rows 1..512 = leaky(F1b @ WFsT + beff); fused column-sum partials
// 1D grid 512: id = b + 32*(seg*2+nt)
__global__ __launch_bounds__(256) void k_fgemm(
    const unsigned short* __restrict__ F1b, const unsigned short* __restrict__ WFsT,
    const float* __restrict__ beffv, float* __restrict__ out, float* __restrict__ msum)
{
    __shared__ unsigned short AsL[8192], BsL[8192];
    __shared__ float msS[64];
    const int t = threadIdx.x;
    const int id = blockIdx.x;
    const int b = id & 31, tt = id >> 5;
    const int seg = tt >> 1, nt = tt & 1;
    if (t < 64) msS[t] = 0.f;                     // pipe's first barrier covers this
    f32x4 acc[2][2];
#pragma unroll
    for (int i = 0; i < 2; i++)
#pragma unroll
        for (int n = 0; n < 2; n++) acc[i][n] = (f32x4){0.f, 0.f, 0.f, 0.f};
    pipe64x64(F1b + ((size_t)b * 512 + seg * 64) * 384, 384,
              WFsT + (size_t)nt * 64 * 384, 384, 6, AsL, BsL, acc, t);

    const int wave = t >> 6, lane = t & 63;
    const int wm = wave >> 1, wn = wave & 1;
    const int quad = lane >> 4, l16 = lane & 15;
    float ls[2];
#pragma unroll
    for (int n = 0; n < 2; n++) ls[n] = 0.f;
#pragma unroll
    for (int i = 0; i < 2; i++) {
        int nd = seg * 64 + wm * 32 + i * 16 + quad * 4;
#pragma unroll
        for (int n = 0; n < 2; n++) {
            int col = nt * 64 + wn * 32 + n * 16 + l16;
            float bb = beffv[col];
#pragma unroll
            for (int r = 0; r < 4; r++) {
                float x = acc[i][n][r] + bb;
                float v = LEAKY(x);
                out[(size_t)b * 65664 + (size_t)(nd + r + 1) * 128 + col] = v;
                ls[n] += v;
            }
        }
    }
#pragma unroll
    for (int n = 0; n < 2; n++) atomicAdd(&msS[wn * 32 + n * 16 + l16], ls[n]);
    __syncthreads();
    if (t < 64) atomicAdd(&msum[b * 128 + nt * 64 + t], msS[t]);
}

// depot row + final means
__global__ void k_meandep(const float* __restrict__ depot, const float* __restrict__ Wd,
                          const float* __restrict__ bd, const float* __restrict__ msum,
                          float* __restrict__ out) {
    int id = blockIdx.x * 256 + threadIdx.x;   // 4096
    int b = id >> 7, o = id & 127;
    float dep = depot[b * 2] * Wd[o] + depot[b * 2 + 1] * Wd[128 + o] + bd[o];
    out[(size_t)b * 65664 + o] = dep;
    out[2101248 + id] = (msum[id] + dep) * (1.0f / 513.0f);
}

// ---------------- launch ----------------

extern "C" void kernel_launch(void* const* d_in, const int* in_sizes, int n_in,
                              void* d_out, int out_size, void* d_ws, size_t ws_size,
                              hipStream_t stream) {
    const float* loc      = (const float*)d_in[0];
    const float* deadline = (const float*)d_in[1];
    const float* depot    = (const float*)d_in[3];
    const float* W_init   = (const float*)d_in[4];
    const float* b_init   = (const float*)d_in[5];
    const float* W_dep    = (const float*)d_in[6];
    const float* b_dep    = (const float*)d_in[7];
    const float* W_g1     = (const float*)d_in[8];
    const float* b_g1     = (const float*)d_in[9];
    const float* W_g2     = (const float*)d_in[10];
    const float* b_g2     = (const float*)d_in[11];
    const float* W_g3     = (const float*)d_in[12];
    const float* b_g3     = (const float*)d_in[13];
    const float* gamma    = (const float*)d_in[14];
    const float* beta     = (const float*)d_in[15];
    const float* W_F      = (const float*)d_in[16];
    const float* b_F      = (const float*)d_in[17];
    float* out = (float*)d_out;
    float* ws  = (float*)d_ws;

    // workspace (float offsets, 16B aligned); ~93 MB
    float* dmaxv  = ws + 0;         // 4
    float* pmax64 = ws + 4;         // 64
    float* bn1    = ws + 68;        // 384
    float* bn2    = ws + 452;       // 384
    float* msum   = ws + 836;       // 4096
    float* rowsum = ws + 4932;      // 16384
    float* beffv  = ws + 21316;     // 128 (+4 pad)
    unsigned short* Lb   = (unsigned short*)(ws + 21448);     // 8388608 u16
    unsigned short* P1   = (unsigned short*)(ws + 4215752);   // 6291456 u16
    unsigned short* P2   = (unsigned short*)(ws + 7361480);
    unsigned short* P3   = (unsigned short*)(ws + 10507208);
    unsigned short* WgT  = (unsigned short*)(ws + 13652936);  // 442368 u16
    unsigned short* WFsT = (unsigned short*)(ws + 13874120);  // 49152 u16
    unsigned short* Y2T  = (unsigned short*)(ws + 13898696);  // 6291456 u16
    unsigned short* ZT   = (unsigned short*)(ws + 17044424);
    unsigned short* F1b  = (unsigned short*)(ws + 20190152);

    // zero: dmaxv, pmax64, bn1, bn2, msum  (contiguous low region)
    hipMemsetAsync(ws, 0, 4932 * sizeof(float), stream);

    k_dmax<<<64, 256, 0, stream>>>(deadline, dmaxv);
    k_rowstats<<<4096, 256, 0, stream>>>(loc, deadline, dmaxv, rowsum, pmax64);
    k_build<<<16064, 256, 0, stream>>>(loc, deadline, dmaxv, rowsum, pmax64,
                                       W_init, b_init, W_g1, W_g2, W_g3,
                                       Lb, P1, P2, P3, WgT);

    k_ygemmT<<<384, 256, 0, stream>>>(WgT, P1, P2, P3, Y2T);
    k_lg1T<<<384, 256, 0, stream>>>(Lb, Y2T, WgT, P1, P2, P3, ZT);
    k_lg2<<<384, 256, 0, stream>>>(Lb, ZT, WgT, P1, P2, P3,
                                   b_g1, b_g2, b_g3, F1b, bn1, bn2);

    k_bnfold<<<193, 256, 0, stream>>>(bn1, bn2, gamma, beta, W_F, b_F, WFsT, beffv);
    k_fgemm<<<512, 256, 0, stream>>>(F1b, WFsT, beffv, out, msum);
    k_meandep<<<16, 256, 0, stream>>>(depot, W_dep, b_dep, msum, out);
}

// Round 3
// 221.995 us; speedup vs baseline: 1.0875x; 1.0875x over previous
//
#include <hip/hip_runtime.h>

#define LEAKY(x) ((x) > 0.0f ? (x) : 0.01f * (x))

typedef __attribute__((ext_vector_type(8))) short bf16x8;      // MFMA A/B frag
typedef __attribute__((ext_vector_type(4))) float f32x4;       // MFMA C/D frag
typedef __attribute__((ext_vector_type(8))) unsigned short u16x8;
typedef __attribute__((ext_vector_type(4))) unsigned short u16x4;

__device__ __forceinline__ unsigned short f2bf(float f) {
    unsigned int u = __float_as_uint(f);
    unsigned int r = (u + 0x7fffu + ((u >> 16) & 1u)) >> 16;   // RNE
    return (unsigned short)r;
}
__device__ __forceinline__ float bf2f(unsigned short u) {
    return __uint_as_float(((unsigned int)u) << 16);
}

// async global->LDS DMA, 16B per lane. LDS dest is WAVE-UNIFORM base + lane*16;
// global src is per-lane (carries the inverse swizzle).
#define GLD16(gp, lp) __builtin_amdgcn_global_load_lds( \
    (__attribute__((address_space(1))) void*)(gp), \
    (__attribute__((address_space(3))) void*)(lp), 16, 0, 0)

// ---------------- small builds ----------------

// wide max via atomicMax (values > 0 so uint ordering == float ordering); grid 64
__global__ void k_dmax(const float* __restrict__ deadline, float* __restrict__ dmax) {
    int t = threadIdx.x;
    float m = deadline[blockIdx.x * 256 + t];
    for (int off = 32; off > 0; off >>= 1) m = fmaxf(m, __shfl_down(m, off));
    __shared__ float s[4];
    if ((t & 63) == 0) s[t >> 6] = m;
    __syncthreads();
    if (t == 0) atomicMax((unsigned int*)dmax,
                          __float_as_uint(fmaxf(fmaxf(s[0], s[1]), fmaxf(s[2], s[3]))));
}

// rowsum + 64-slot atomicMax partials of r=1/dist; R is NOT materialized
__global__ __launch_bounds__(256) void k_rowstats(const float* __restrict__ loc,
                                                  const float* __restrict__ deadline,
                                                  const float* __restrict__ dmaxv,
                                                  float* __restrict__ rowsum, float* __restrict__ pmax64) {
    int blk = blockIdx.x;                       // 0..4095
    int wave = threadIdx.x >> 6, lane = threadIdx.x & 63;
    int bi = blk * 4 + wave;                    // b*512 + i
    int b = bi >> 9, i = bi & 511;
    float invd = 1.0f / (*dmaxv);
    const float* lb = loc + b * 1024;
    const float* db = deadline + b * 512;
    float xi = lb[i * 2], yi = lb[i * 2 + 1], zi = db[i] * invd;
    float lsum = 0.f, lmax = 0.f;
    for (int j = lane; j < 512; j += 64) {
        float d0 = xi - lb[j * 2], d1 = yi - lb[j * 2 + 1], d2 = zi - db[j] * invd;
        float dd = d0 * d0 + d1 * d1 + d2 * d2;
        float r = (j == i) ? 0.f : rsqrtf(dd);
        lsum += r; lmax = fmaxf(lmax, r);
    }
    for (int off = 32; off > 0; off >>= 1) {
        lsum += __shfl_down(lsum, off);
        lmax = fmaxf(lmax, __shfl_down(lmax, off));
    }
    __shared__ float smax[4];
    if (lane == 0) { rowsum[bi] = lsum; smax[wave] = lmax; }
    __syncthreads();
    if (threadIdx.x == 0) {
        float m = fmaxf(fmaxf(smax[0], smax[1]), fmaxf(smax[2], smax[3]));
        atomicMax((unsigned int*)(pmax64 + (blk & 63)), __float_as_uint(m));
    }
}

// fused build: [0,8192) L ; [8192,14336) F0 powers ; [14336,16064) WgT repack
__global__ __launch_bounds__(256) void k_build(
    const float* __restrict__ loc, const float* __restrict__ deadline,
    const float* __restrict__ dmaxv, const float* __restrict__ rowsum,
    const float* __restrict__ pmax64,
    const float* __restrict__ Wi, const float* __restrict__ bi_,
    const float* __restrict__ Wg1, const float* __restrict__ Wg2, const float* __restrict__ Wg3,
    unsigned short* __restrict__ Lb,
    unsigned short* __restrict__ P1, unsigned short* __restrict__ P2, unsigned short* __restrict__ P3,
    unsigned short* __restrict__ WgT)
{
    __shared__ float amaxS;
    int blk = blockIdx.x;
    int t = threadIdx.x;
    if (blk < 8192) {
        // ---- L bf16 (symmetric), recompute r on the fly: 4 j's per thread ----
        if (t < 64) {
            float m = pmax64[t];
            for (int off = 32; off > 0; off >>= 1) m = fmaxf(m, __shfl_down(m, off));
            if (t == 0) amaxS = m;
        }
        __syncthreads();
        float inv = 1.0f / amaxS;
        float invd = 1.0f / (*dmaxv);
        int id = blk * 256 + t;
        size_t e = (size_t)id * 4;
        size_t bi = e >> 9;
        int b = (int)(bi >> 9);
        int i = (int)(bi & 511);
        int j0 = (int)(e & 511);
        const float* lb = loc + b * 1024;
        const float* db = deadline + b * 512;
        float xi = lb[i * 2], yi = lb[i * 2 + 1], zi = db[i] * invd;
        float4 l01 = *(const float4*)(lb + j0 * 2);
        float4 l23 = *(const float4*)(lb + j0 * 2 + 4);
        float4 dj = *(const float4*)(db + j0);
        float diag = rowsum[bi] * inv - 1.0f;
        float jx[4] = {l01.x, l01.z, l23.x, l23.z};
        float jy[4] = {l01.y, l01.w, l23.y, l23.w};
        float jz[4] = {dj.x * invd, dj.y * invd, dj.z * invd, dj.w * invd};
        u16x4 o;
#pragma unroll
        for (int j = 0; j < 4; j++) {
            float d0 = xi - jx[j], d1 = yi - jy[j], d2 = zi - jz[j];
            float dd = d0 * d0 + d1 * d1 + d2 * d2;
            float v = (i == j0 + j) ? diag : -rsqrtf(dd) * inv;
            o[j] = f2bf(v);
        }
        *(u16x4*)(Lb + e) = o;
    } else if (blk < 14336) {
        // ---- F0 powers, bf16 row-major [16384][384] x3, 4 cols per thread ----
        int id = (blk - 8192) * 256 + t;          // 1,572,864
        int row = id / 96, c4 = (id % 96) * 4;
        float x0 = loc[row * 2], x1 = loc[row * 2 + 1], x2 = deadline[row] / (*dmaxv);
        float4 w0 = *(const float4*)(Wi + c4);
        float4 w1 = *(const float4*)(Wi + 384 + c4);
        float4 w2 = *(const float4*)(Wi + 768 + c4);
        float4 bb = *(const float4*)(bi_ + c4);
        float f[4] = {x0 * w0.x + x1 * w1.x + x2 * w2.x + bb.x,
                      x0 * w0.y + x1 * w1.y + x2 * w2.y + bb.y,
                      x0 * w0.z + x1 * w1.z + x2 * w2.z + bb.z,
                      x0 * w0.w + x1 * w1.w + x2 * w2.w + bb.w};
        u16x4 o1, o2, o3;
#pragma unroll
        for (int j = 0; j < 4; j++) {
            o1[j] = f2bf(f[j]); o2[j] = f2bf(f[j] * f[j]); o3[j] = f2bf(f[j] * f[j] * f[j]);
        }
        size_t e = (size_t)row * 384 + c4;
        *(u16x4*)(P1 + e) = o1; *(u16x4*)(P2 + e) = o2; *(u16x4*)(P3 + e) = o3;
    } else {
        // ---- WgT[part][g][k] = Wg{g/128}[(part*384+k)*128 + (g&127)] ----
        int id = (blk - 14336) * 256 + t;         // 442368 exact
        int part = id / 147456, rem = id % 147456;
        int g = rem / 384, k = rem % 384;
        int kp = g >> 7, n = g & 127;
        const float* W = (kp == 0) ? Wg1 : (kp == 1 ? Wg2 : Wg3);
        WgT[id] = f2bf(W[(part * 384 + k) * 128 + n]);
    }
}

// ---------------- pipelined MFMA cores: counted-vmcnt, 2-deep prefetch ----------------
// T4 structure: raw s_barrier + s_waitcnt vmcnt(N) with N = instrs of the NEWEST tile
// still allowed in flight -> loads for tile s+1 stay outstanding ACROSS barriers; tile
// s+2's DMA issues under the MFMAs. vmcnt never drains to 0 in steady state.
// Per iter: vmcnt(W); bar; [frag ds_reads]; lgkmcnt(0); bar; stage(s+2); MFMAs.
// Swizzle (rule #21): LDS dest linear, global SOURCE pre-swizzled per lane with the
// same involution (chunk ^= row&7) the ds_read side uses.
// 128x128 tile: 4 waves 2x2, wave tile 64x64 (4x4 frags), 32 MFMA/wave/iter.

__device__ __forceinline__ void pipe128x128(
    const unsigned short* __restrict__ A0, int As0, const unsigned short* __restrict__ B0, int Bs0, int it0,
    const unsigned short* __restrict__ A1, int As1, const unsigned short* __restrict__ B1, int Bs1, int it1,
    unsigned short* AsL, unsigned short* BsL,   // each 16384 u16 (2 bufs x 8192)
    f32x4 (&acc)[4][4], int t)
{
    const int lane = t & 63, wave = t >> 6;
    const int wm = wave >> 1, wn = wave & 1;
    const int quad = lane >> 4, l16 = lane & 15;
    const int lrow = lane >> 3;                  // 0..7 row within 8-row stripe
    const int lsw  = ((lane & 7) ^ lrow) * 8;    // inverse-swizzled src chunk (u16 units)
    const int total = it0 + it1;

    auto stage = [&](int buf, int s) {           // 8 DMA instr / wave / tile
        int sg = (s >= it0);
        const unsigned short* A = sg ? A1 : A0;
        const unsigned short* B = sg ? B1 : B0;
        int As = sg ? As1 : As0, Bs = sg ? Bs1 : Bs0;
        int k0 = (sg ? (s - it0) : s) * 64;
#pragma unroll
        for (int j = 0; j < 4; j++) {            // 128 rows A + 128 rows B, 8 rows/DMA
            int r0 = wave * 32 + j * 8;
            GLD16(A + (size_t)(r0 + lrow) * As + k0 + lsw, AsL + buf * 8192 + r0 * 64);
            GLD16(B + (size_t)(r0 + lrow) * Bs + k0 + lsw, BsL + buf * 8192 + r0 * 64);
        }
    };

    stage(0, 0);
    if (total > 1) stage(1, 1);
    for (int s = 0; s < total; s++) {
        const int buf = s & 1;
        // tile s landed (8 newest = tile s+1 may stay in flight); extra older strays only over-wait
        if (s + 1 < total) asm volatile("s_waitcnt vmcnt(8)" ::: "memory");
        else               asm volatile("s_waitcnt vmcnt(0)" ::: "memory");
        __builtin_amdgcn_s_barrier();             // ALL waves' tile-s DMA visible
        __builtin_amdgcn_sched_barrier(0);
        bf16x8 af[2][4], bfr[2][4];
#pragma unroll
        for (int h = 0; h < 2; h++) {
            int phys = ((h * 4 + quad) ^ (l16 & 7)) * 8;
#pragma unroll
            for (int i = 0; i < 4; i++)
                af[h][i] = *(const bf16x8*)(AsL + buf * 8192 + (wm * 64 + i * 16 + l16) * 64 + phys);
#pragma unroll
            for (int n = 0; n < 4; n++)
                bfr[h][n] = *(const bf16x8*)(BsL + buf * 8192 + (wn * 64 + n * 16 + l16) * 64 + phys);
        }
        asm volatile("s_waitcnt lgkmcnt(0)" ::: "memory");   // frag reads retired
        __builtin_amdgcn_sched_barrier(0);
        __builtin_amdgcn_s_barrier();             // all waves done READING buf
        __builtin_amdgcn_sched_barrier(0);
        if (s + 2 < total) stage(buf, s + 2);     // refill freed buf under the MFMAs
#pragma unroll
        for (int h = 0; h < 2; h++)
#pragma unroll
            for (int i = 0; i < 4; i++)
#pragma unroll
                for (int n = 0; n < 4; n++)
                    acc[i][n] = __builtin_amdgcn_mfma_f32_16x16x32_bf16(af[h][i], bfr[h][n], acc[i][n], 0, 0, 0);
    }
}

// 64x64 tile: wave tile 32x32 (2x2 frags), 8 MFMA/wave/iter
__device__ __forceinline__ void pipe64x64(
    const unsigned short* __restrict__ A0, int As0, const unsigned short* __restrict__ B0, int Bs0, int it0,
    unsigned short* AsL, unsigned short* BsL,   // 8192 / 8192 u16
    f32x4 (&acc)[2][2], int t)
{
    const int lane = t & 63, wave = t >> 6;
    const int wm = wave >> 1, wn = wave & 1;
    const int quad = lane >> 4, l16 = lane & 15;
    const int lrow = lane >> 3;
    const int lsw  = ((lane & 7) ^ lrow) * 8;

    auto stage = [&](int buf, int s) {           // 4 DMA instr / wave / tile
        int k0 = s * 64;
#pragma unroll
        for (int j = 0; j < 2; j++) {
            int r0 = wave * 16 + j * 8;
            GLD16(A0 + (size_t)(r0 + lrow) * As0 + k0 + lsw, AsL + buf * 4096 + r0 * 64);
            GLD16(B0 + (size_t)(r0 + lrow) * Bs0 + k0 + lsw, BsL + buf * 4096 + r0 * 64);
        }
    };

    stage(0, 0);
    if (it0 > 1) stage(1, 1);
    for (int s = 0; s < it0; s++) {
        const int buf = s & 1;
        if (s + 1 < it0) asm volatile("s_waitcnt vmcnt(4)" ::: "memory");
        else             asm volatile("s_waitcnt vmcnt(0)" ::: "memory");
        __builtin_amdgcn_s_barrier();
        __builtin_amdgcn_sched_barrier(0);
        bf16x8 af[2][2], bfr[2][2];
#pragma unroll
        for (int h = 0; h < 2; h++) {
            int phys = ((h * 4 + quad) ^ (l16 & 7)) * 8;
#pragma unroll
            for (int i = 0; i < 2; i++)
                af[h][i] = *(const bf16x8*)(AsL + buf * 4096 + (wm * 32 + i * 16 + l16) * 64 + phys);
#pragma unroll
            for (int n = 0; n < 2; n++)
                bfr[h][n] = *(const bf16x8*)(BsL + buf * 4096 + (wn * 32 + n * 16 + l16) * 64 + phys);
        }
        asm volatile("s_waitcnt lgkmcnt(0)" ::: "memory");
        __builtin_amdgcn_sched_barrier(0);
        __builtin_amdgcn_s_barrier();
        __builtin_amdgcn_sched_barrier(0);
        if (s + 2 < it0) stage(buf, s + 2);
#pragma unroll
        for (int h = 0; h < 2; h++)
#pragma unroll
            for (int i = 0; i < 2; i++)
#pragma unroll
                for (int n = 0; n < 2; n++)
                    acc[i][n] = __builtin_amdgcn_mfma_f32_16x16x32_bf16(af[h][i], bfr[h][n], acc[i][n], 0, 0, 0);
    }
}

// Y2^T[g][node] = WgT(p2)·P^T ; grid 384, id = b + 32*(kp*4+nb)
__global__ __launch_bounds__(256) void k_ygemmT(
    const unsigned short* __restrict__ WgT,
    const unsigned short* __restrict__ P1, const unsigned short* __restrict__ P2,
    const unsigned short* __restrict__ P3, unsigned short* __restrict__ Y2T)
{
    __shared__ unsigned short AsL[16384], BsL[16384];
    const int t = threadIdx.x;
    const int id = blockIdx.x;
    const int b = id & 31, tt = id >> 5;
    const int kp = tt >> 2, nb = tt & 3;
    const unsigned short* P = (kp == 0) ? P1 : (kp == 1 ? P2 : P3);
    f32x4 acc[4][4];
#pragma unroll
    for (int i = 0; i < 4; i++)
#pragma unroll
        for (int n = 0; n < 4; n++) acc[i][n] = (f32x4){0.f, 0.f, 0.f, 0.f};
    pipe128x128(WgT + ((size_t)2 * 384 + kp * 128) * 384, 384,
                P + ((size_t)b * 512 + nb * 128) * 384, 384, 6,
                nullptr, 0, nullptr, 0, 0, AsL, BsL, acc, t);

    const int wave = t >> 6, lane = t & 63;
    const int wm = wave >> 1, wn = wave & 1;
    const int quad = lane >> 4, l16 = lane & 15;
#pragma unroll
    for (int i = 0; i < 4; i++)
#pragma unroll
        for (int n = 0; n < 4; n++) {
            int g = kp * 128 + wm * 64 + i * 16 + quad * 4;
            int node = nb * 128 + wn * 64 + n * 16 + l16;
#pragma unroll
            for (int r = 0; r < 4; r++)
                Y2T[((size_t)b * 384 + g + r) * 512 + node] = f2bf(acc[i][n][r]);
        }
}

// Z^T = Y2T·L + WgT(p1)·P^T ; grid 384
__global__ __launch_bounds__(256) void k_lg1T(
    const unsigned short* __restrict__ Lb, const unsigned short* __restrict__ Y2T,
    const unsigned short* __restrict__ WgT,
    const unsigned short* __restrict__ P1, const unsigned short* __restrict__ P2,
    const unsigned short* __restrict__ P3, unsigned short* __restrict__ ZT)
{
    __shared__ unsigned short AsL[16384], BsL[16384];
    const int t = threadIdx.x;
    const int id = blockIdx.x;
    const int b = id & 31, tt = id >> 5;
    const int kp = tt >> 2, nb = tt & 3;
    const unsigned short* P = (kp == 0) ? P1 : (kp == 1 ? P2 : P3);
    f32x4 acc[4][4];
#pragma unroll
    for (int i = 0; i < 4; i++)
#pragma unroll
        for (int n = 0; n < 4; n++) acc[i][n] = (f32x4){0.f, 0.f, 0.f, 0.f};
    pipe128x128(Y2T + (size_t)b * 196608 + (size_t)kp * 128 * 512, 512,
                Lb + (size_t)b * 262144 + (size_t)nb * 128 * 512, 512, 8,
                WgT + ((size_t)1 * 384 + kp * 128) * 384, 384,
                P + ((size_t)b * 512 + nb * 128) * 384, 384, 6, AsL, BsL, acc, t);

    const int wave = t >> 6, lane = t & 63;
    const int wm = wave >> 1, wn = wave & 1;
    const int quad = lane >> 4, l16 = lane & 15;
#pragma unroll
    for (int i = 0; i < 4; i++)
#pragma unroll
        for (int n = 0; n < 4; n++) {
            int g = kp * 128 + wm * 64 + i * 16 + quad * 4;
            int node = nb * 128 + wn * 64 + n * 16 + l16;
#pragma unroll
            for (int r = 0; r < 4; r++)
                ZT[((size_t)b * 384 + g + r) * 512 + node] = f2bf(acc[i][n][r]);
        }
}

// F1 = leaky(L·Z + P·WgT(p0)^T + bias) + F0 ; fused BN sums ; grid 384, tt = gt*4+mb
__global__ __launch_bounds__(256) void k_lg2(
    const unsigned short* __restrict__ Lb, const unsigned short* __restrict__ ZT,
    const unsigned short* __restrict__ WgT,
    const unsigned short* __restrict__ P1, const unsigned short* __restrict__ P2,
    const unsigned short* __restrict__ P3,
    const float* __restrict__ bg1, const float* __restrict__ bg2, const float* __restrict__ bg3,
    unsigned short* __restrict__ F1b, float* __restrict__ bn1, float* __restrict__ bn2)
{
    __shared__ unsigned short AsL[16384], BsL[16384];
    __shared__ float bnS[128], bnQ[128];
    const int t = threadIdx.x;
    const int id = blockIdx.x;
    const int b = id & 31, tt = id >> 5;
    const int mb = tt & 3, gt = tt >> 2;          // mb: node tile(128), gt=kp: gcol tile(128) 0..2
    if (t < 128) { bnS[t] = 0.f; bnQ[t] = 0.f; }  // pipe's first barrier covers this
    const unsigned short* P = (gt == 0) ? P1 : (gt == 1 ? P2 : P3);
    f32x4 acc[4][4];
#pragma unroll
    for (int i = 0; i < 4; i++)
#pragma unroll
        for (int n = 0; n < 4; n++) acc[i][n] = (f32x4){0.f, 0.f, 0.f, 0.f};
    pipe128x128(Lb + (size_t)b * 262144 + (size_t)mb * 128 * 512, 512,
                ZT + (size_t)b * 196608 + (size_t)gt * 128 * 512, 512, 8,
                P + ((size_t)b * 512 + mb * 128) * 384, 384,
                WgT + (size_t)(gt * 128) * 384, 384, 6,
                AsL, BsL, acc, t);

    const int wave = t >> 6, lane = t & 63;
    const int wm = wave >> 1, wn = wave & 1;
    const int quad = lane >> 4, l16 = lane & 15;
    const float* bg = (gt == 0) ? bg1 : (gt == 1 ? bg2 : bg3);
    float ls1[4], ls2[4];
#pragma unroll
    for (int n = 0; n < 4; n++) { ls1[n] = 0.f; ls2[n] = 0.f; }
#pragma unroll
    for (int i = 0; i < 4; i++) {
        int rowl = mb * 128 + wm * 64 + i * 16 + quad * 4;
        size_t rowg = (size_t)b * 512 + rowl;
#pragma unroll
        for (int n = 0; n < 4; n++) {
            int nloc = wn * 64 + n * 16 + l16;    // 0..127
            int g = gt * 128 + nloc;
            float bias = bg[nloc];
#pragma unroll
            for (int r = 0; r < 4; r++) {
                size_t idx = (rowg + r) * 384 + g;
                float c = acc[i][n][r] + bias;
                float v = LEAKY(c) + bf2f(P1[idx]);   // residual +F0
                F1b[idx] = f2bf(v);
                ls1[n] += v; ls2[n] += v * v;
            }
        }
    }
#pragma unroll
    for (int n = 0; n < 4; n++) {
        int nloc = wn * 64 + n * 16 + l16;
        atomicAdd(&bnS[nloc], ls1[n]);
        atomicAdd(&bnQ[nloc], ls2[n]);
    }
    __syncthreads();
    if (t < 128) {
        atomicAdd(&bn1[gt * 128 + t], bnS[t]);
        atomicAdd(&bn2[gt * 128 + t], bnQ[t]);
    }
}

// merged: BN finish + fold scale into W_F^T (blocks 0..191) + effective bias (block 192)
__global__ __launch_bounds__(256) void k_bnfold(
    const float* __restrict__ bn1, const float* __restrict__ bn2,
    const float* __restrict__ gamma, const float* __restrict__ beta,
    const float* __restrict__ WF, const float* __restrict__ bF,
    unsigned short* __restrict__ WFsT, float* __restrict__ beffv)
{
    int blk = blockIdx.x;
    if (blk < 192) {                              // WFsT[n][k] = W_F[k][n]*sc[k]
        int id = blk * 256 + threadIdx.x;         // 49152
        int n = id / 384, k = id % 384;
        float mu = bn1[k] * (1.f / 16384.f);
        float var = bn2[k] * (1.f / 16384.f) - mu * mu;
        float sc = gamma[k] / sqrtf(var + 1e-5f);
        WFsT[id] = f2bf(WF[k * 128 + n] * sc);
    } else {                                      // beff[c] = bF[c] + sum_k ttL[k]*WF[k][c]
        __shared__ float ttL[384];
        int c = threadIdx.x;
        for (int k = c; k < 384; k += 256) {
            float mu = bn1[k] * (1.f / 16384.f);
            float var = bn2[k] * (1.f / 16384.f) - mu * mu;
            float sc = gamma[k] / sqrtf(var + 1e-5f);
            ttL[k] = beta[k] - mu * sc;
        }
        __syncthreads();
        if (c < 128) {
            float a = bF[c];
            for (int k = 0; k < 384; k++) a += ttL[k] * WF[k * 128 + c];
            beffv[c] = a;
        }
    }
}

// out rows 1..512 = leaky(F1b @ WFsT + beff); fused column-sum partials
// 1D grid 512: id = b + 32*(seg*2+nt)
__global__ __launch_bounds__(256) void k_fgemm(
    const unsigned short* __restrict__ F1b, const unsigned short* __restrict__ WFsT,
    const float* __restrict__ beffv, float* __restrict__ out, float* __restrict__ msum)
{
    __shared__ unsigned short AsL[8192], BsL[8192];
    __shared__ float msS[64];
    const int t = threadIdx.x;
    const int id = blockIdx.x;
    const int b = id & 31, tt = id >> 5;
    const int seg = tt >> 1, nt = tt & 1;
    if (t < 64) msS[t] = 0.f;                     // pipe's first barrier covers this
    f32x4 acc[2][2];
#pragma unroll
    for (int i = 0; i < 2; i++)
#pragma unroll
        for (int n = 0; n < 2; n++) acc[i][n] = (f32x4){0.f, 0.f, 0.f, 0.f};
    pipe64x64(F1b + ((size_t)b * 512 + seg * 64) * 384, 384,
              WFsT + (size_t)nt * 64 * 384, 384, 6, AsL, BsL, acc, t);

    const int wave = t >> 6, lane = t & 63;
    const int wm = wave >> 1, wn = wave & 1;
    const int quad = lane >> 4, l16 = lane & 15;
    float ls[2];
#pragma unroll
    for (int n = 0; n < 2; n++) ls[n] = 0.f;
#pragma unroll
    for (int i = 0; i < 2; i++) {
        int nd = seg * 64 + wm * 32 + i * 16 + quad * 4;
#pragma unroll
        for (int n = 0; n < 2; n++) {
            int col = nt * 64 + wn * 32 + n * 16 + l16;
            float bb = beffv[col];
#pragma unroll
            for (int r = 0; r < 4; r++) {
                float x = acc[i][n][r] + bb;
                float v = LEAKY(x);
                out[(size_t)b * 65664 + (size_t)(nd + r + 1) * 128 + col] = v;
                ls[n] += v;
            }
        }
    }
#pragma unroll
    for (int n = 0; n < 2; n++) atomicAdd(&msS[wn * 32 + n * 16 + l16], ls[n]);
    __syncthreads();
    if (t < 64) atomicAdd(&msum[b * 128 + nt * 64 + t], msS[t]);
}

// depot row + final means
__global__ void k_meandep(const float* __restrict__ depot, const float* __restrict__ Wd,
                          const float* __restrict__ bd, const float* __restrict__ msum,
                          float* __restrict__ out) {
    int id = blockIdx.x * 256 + threadIdx.x;   // 4096
    int b = id >> 7, o = id & 127;
    float dep = depot[b * 2] * Wd[o] + depot[b * 2 + 1] * Wd[128 + o] + bd[o];
    out[(size_t)b * 65664 + o] = dep;
    out[2101248 + id] = (msum[id] + dep) * (1.0f / 513.0f);
}

// ---------------- launch ----------------

extern "C" void kernel_launch(void* const* d_in, const int* in_sizes, int n_in,
                              void* d_out, int out_size, void* d_ws, size_t ws_size,
                              hipStream_t stream) {
    const float* loc      = (const float*)d_in[0];
    const float* deadline = (const float*)d_in[1];
    const float* depot    = (const float*)d_in[3];
    const float* W_init   = (const float*)d_in[4];
    const float* b_init   = (const float*)d_in[5];
    const float* W_dep    = (const float*)d_in[6];
    const float* b_dep    = (const float*)d_in[7];
    const float* W_g1     = (const float*)d_in[8];
    const float* b_g1     = (const float*)d_in[9];
    const float* W_g2     = (const float*)d_in[10];
    const float* b_g2     = (const float*)d_in[11];
    const float* W_g3     = (const float*)d_in[12];
    const float* b_g3     = (const float*)d_in[13];
    const float* gamma    = (const float*)d_in[14];
    const float* beta     = (const float*)d_in[15];
    const float* W_F      = (const float*)d_in[16];
    const float* b_F      = (const float*)d_in[17];
    float* out = (float*)d_out;
    float* ws  = (float*)d_ws;

    // workspace (float offsets, 16B aligned); ~93 MB
    float* dmaxv  = ws + 0;         // 4
    float* pmax64 = ws + 4;         // 64
    float* bn1    = ws + 68;        // 384
    float* bn2    = ws + 452;       // 384
    float* msum   = ws + 836;       // 4096
    float* rowsum = ws + 4932;      // 16384
    float* beffv  = ws + 21316;     // 128 (+4 pad)
    unsigned short* Lb   = (unsigned short*)(ws + 21448);     // 8388608 u16
    unsigned short* P1   = (unsigned short*)(ws + 4215752);   // 6291456 u16
    unsigned short* P2   = (unsigned short*)(ws + 7361480);
    unsigned short* P3   = (unsigned short*)(ws + 10507208);
    unsigned short* WgT  = (unsigned short*)(ws + 13652936);  // 442368 u16
    unsigned short* WFsT = (unsigned short*)(ws + 13874120);  // 49152 u16
    unsigned short* Y2T  = (unsigned short*)(ws + 13898696);  // 6291456 u16
    unsigned short* ZT   = (unsigned short*)(ws + 17044424);
    unsigned short* F1b  = (unsigned short*)(ws + 20190152);

    // zero: dmaxv, pmax64, bn1, bn2, msum  (contiguous low region)
    hipMemsetAsync(ws, 0, 4932 * sizeof(float), stream);

    k_dmax<<<64, 256, 0, stream>>>(deadline, dmaxv);
    k_rowstats<<<4096, 256, 0, stream>>>(loc, deadline, dmaxv, rowsum, pmax64);
    k_build<<<16064, 256, 0, stream>>>(loc, deadline, dmaxv, rowsum, pmax64,
                                       W_init, b_init, W_g1, W_g2, W_g3,
                                       Lb, P1, P2, P3, WgT);

    k_ygemmT<<<384, 256, 0, stream>>>(WgT, P1, P2, P3, Y2T);
    k_lg1T<<<384, 256, 0, stream>>>(Lb, Y2T, WgT, P1, P2, P3, ZT);
    k_lg2<<<384, 256, 0, stream>>>(Lb, ZT, WgT, P1, P2, P3,
                                   b_g1, b_g2, b_g3, F1b, bn1, bn2);

    k_bnfold<<<193, 256, 0, stream>>>(bn1, bn2, gamma, beta, W_F, b_F, WFsT, beffv);
    k_fgemm<<<512, 256, 0, stream>>>(F1b, WFsT, beffv, out, msum);
    k_meandep<<<16, 256, 0, stream>>>(depot, W_dep, b_dep, msum, out);
}